// Round 4
// baseline (177.747 us; speedup 1.0000x reference)
//
#include <hip/hip_runtime.h>

#define NB   8192
#define NT   2048
#define OBS  30
#define LCH  32               // chunk length
#define CCH  64               // chunks per row (LCH*CCH == NT)
#define NCHAIN (NB*CCH)       // 524288 independent chains
#define NBLKA  (NCHAIN/256)   // 2048 work blocks

// One scratch buffer, in-place: passA writes particular finals p_c, k_scan
// overwrites with true chunk-start states s_c, passC reads. [(b*CCH+c)*32+k]
__device__ float g_ps[(size_t)NCHAIN * 32];
// C[t][k] = homogeneous output at local step t from unit state e_k (32x32).
// A^LCH row i = C[LCH-OBS+i] = C[2+i].
__device__ float g_C[32 * 32];

// One recurrence step on a 32-slot register ring, 6 accumulator chains.
// Invariant: before step t, state s_t[i] lives at r[(t+i)&31], i=0..29.
// j == t mod 32 must be a compile-time constant (callers fully unroll).
__device__ __forceinline__ float step6(float (&r)[32], const float (&wx)[OBS],
                                       int j, float uwf) {
  float a0 = fmaf(wx[0], r[(j + 0) & 31], uwf);
  float a1 = wx[1] * r[(j + 1) & 31];
  float a2 = wx[2] * r[(j + 2) & 31];
  float a3 = wx[3] * r[(j + 3) & 31];
  float a4 = wx[4] * r[(j + 4) & 31];
  float a5 = wx[5] * r[(j + 5) & 31];
  #pragma unroll
  for (int i = 6; i < OBS; i += 6) {
    a0 += wx[i]     * r[(j + i)     & 31];
    a1 += wx[i + 1] * r[(j + i + 1) & 31];
    a2 += wx[i + 2] * r[(j + i + 2) & 31];
    a3 += wx[i + 3] * r[(j + i + 3) & 31];
    a4 += wx[i + 4] * r[(j + i + 4) & 31];
    a5 += wx[i + 5] * r[(j + i + 5) & 31];
  }
  float out = ((a0 + a1) + (a2 + a3)) + (a4 + a5);
  r[(j + 30) & 31] = out;   // becomes s_{t+1}[29]
  return out;
}

// C matrix via unit-state chains; run by lanes 0..31 of one extra passA block.
__device__ __forceinline__ void compute_C(const float* __restrict__ Wx) {
  int k = threadIdx.x;
  if (k >= 32) return;
  float wx[OBS];
  #pragma unroll
  for (int i = 0; i < OBS; ++i) wx[i] = Wx[i];
  float r[32];
  #pragma unroll
  for (int i = 0; i < 32; ++i) r[i] = (k < OBS && i == k) ? 1.f : 0.f;
  #pragma unroll
  for (int j = 0; j < LCH; ++j)
    g_C[j * 32 + k] = step6(r, wx, j, 0.f);
}

// ---- pass A: zero-init chunk recurrence -> particular final states p_c ----
__global__ void __launch_bounds__(256) k_passA(const float* __restrict__ u,
                                               const float* __restrict__ Wx,
                                               const float* __restrict__ Wf) {
  if (blockIdx.x == NBLKA) { compute_C(Wx); return; }
  const int n = blockIdx.x * 256 + threadIdx.x;   // chain = b*CCH + c
  float wx[OBS];
  #pragma unroll
  for (int i = 0; i < OBS; ++i) wx[i] = Wx[i];
  const float wf = Wf[0];
  float r[32];
  #pragma unroll
  for (int i = 0; i < 32; ++i) r[i] = 0.f;
  const float4* up = (const float4*)(u + (size_t)n * LCH);
  #pragma unroll
  for (int q = 0; q < 8; ++q) {
    float4 u4 = up[q];
    step6(r, wx, q * 4 + 0, wf * u4.x);
    step6(r, wx, q * 4 + 1, wf * u4.y);
    step6(r, wx, q * 4 + 2, wf * u4.z);
    step6(r, wx, q * 4 + 3, wf * u4.w);
  }
  // s_32[i] == r[i] (32 steps -> ring realigned); r[30],r[31] junk-but-finite
  float4* pv = (float4*)(g_ps + (size_t)n * 32);
  #pragma unroll
  for (int q = 0; q < 8; ++q)
    pv[q] = make_float4(r[4 * q], r[4 * q + 1], r[4 * q + 2], r[4 * q + 3]);
}

// ---- scan: s_{c+1} = A^L s_c + p_c, in place over g_ps; 32 lanes/row ----
__global__ void __launch_bounds__(256) k_scan(const float* __restrict__ x0) {
  const int tid = blockIdx.x * 256 + threadIdx.x;
  const int b = tid >> 5, k = tid & 31;
  float arow[32];
  #pragma unroll
  for (int j = 0; j < 32; ++j)
    arow[j] = (k < OBS) ? g_C[(LCH - OBS + k) * 32 + j] : 0.f;
  float s = (k < OBS) ? x0[(size_t)b * OBS + k] : 0.f;
  const size_t base = (size_t)b * CCH * 32 + k;
  float pn = g_ps[base];                       // prefetch c=0
  #pragma unroll 1
  for (int c = 0; c < CCH; ++c) {
    float p = (k < OBS) ? pn : 0.f;
    if (c + 1 < CCH) pn = g_ps[base + (size_t)(c + 1) * 32];  // off serial path
    g_ps[base + (size_t)c * 32] = s;           // overwrite p_c with s_c
    float acc = p;
    #pragma unroll
    for (int j = 0; j < OBS; ++j)
      acc += arow[j] * __shfl(s, j, 32);
    s = acc;
  }
}

// ---- pass C: re-run each chunk from true start state, write outputs ----
__global__ void __launch_bounds__(256) k_passC(const float* __restrict__ u,
                                               const float* __restrict__ Wx,
                                               const float* __restrict__ Wf,
                                               float* __restrict__ out) {
  const int n = blockIdx.x * 256 + threadIdx.x;
  float wx[OBS];
  #pragma unroll
  for (int i = 0; i < OBS; ++i) wx[i] = Wx[i];
  const float wf = Wf[0];
  float r[32];
  const float4* sp = (const float4*)(g_ps + (size_t)n * 32);
  #pragma unroll
  for (int q = 0; q < 8; ++q) {
    float4 v = sp[q];
    r[4 * q] = v.x; r[4 * q + 1] = v.y; r[4 * q + 2] = v.z; r[4 * q + 3] = v.w;
  }
  // r[30],r[31] junk: step j=0 reads only r[0..29]; r[30] written at j=0,
  // r[31] at j=1 before any read. Finite values, so safe.
  const float4* up = (const float4*)(u + (size_t)n * LCH);
  float4*       op = (float4*)(out + (size_t)n * LCH);
  #pragma unroll
  for (int q = 0; q < 8; ++q) {
    float4 u4 = up[q];
    float4 o4;
    o4.x = step6(r, wx, q * 4 + 0, wf * u4.x);
    o4.y = step6(r, wx, q * 4 + 1, wf * u4.y);
    o4.z = step6(r, wx, q * 4 + 2, wf * u4.z);
    o4.w = step6(r, wx, q * 4 + 3, wf * u4.w);
    op[q] = o4;
  }
}

extern "C" void kernel_launch(void* const* d_in, const int* in_sizes, int n_in,
                              void* d_out, int out_size, void* d_ws, size_t ws_size,
                              hipStream_t stream) {
  const float* u  = (const float*)d_in[0];
  const float* x0 = (const float*)d_in[1];
  const float* Wx = (const float*)d_in[2];
  const float* Wf = (const float*)d_in[3];
  float* out = (float*)d_out;

  hipLaunchKernelGGL(k_passA, dim3(NBLKA + 1),      dim3(256), 0, stream, u, Wx, Wf);
  hipLaunchKernelGGL(k_scan,  dim3(NB * 32 / 256),  dim3(256), 0, stream, x0);
  hipLaunchKernelGGL(k_passC, dim3(NBLKA),          dim3(256), 0, stream, u, Wx, Wf, out);
}

// Round 5
// 107.035 us; speedup vs baseline: 1.6606x; 1.6606x over previous
//
#include <hip/hip_runtime.h>

#define NB   8192
#define NT   2048
#define OBS  30
#define LCH  64               // chunk length
#define CCH  32               // chunks per row (LCH*CCH == NT)
#define NCHAIN (NB*CCH)       // 262144 chains
#define NBLK   (NCHAIN/256)   // 1024 work blocks
#define PAD  36               // LDS row stride (floats): 144B, 16B-aligned for b128

// Scratch: passA writes particular chunk-final states p_c, k_scan overwrites
// in place with true chunk-start states s_c, passC reads. [(b*CCH+c)*32+k]
__device__ float g_ps[(size_t)NCHAIN * 32];
__device__ float g_A [OBS * 32];   // A^64: g_A[i*32+j] = coeff s_c[j] -> s_{c+1}[i]

// One recurrence step on a 32-slot register ring, 6 accumulator chains.
// Invariant: before step t, state s_t[i] lives at r[(t+i)&31], i=0..29.
// j == t mod 32 must be a compile-time constant (callers fully unroll).
__device__ __forceinline__ float step6(float (&r)[32], const float (&wx)[OBS],
                                       int j, float uwf) {
  float a0 = fmaf(wx[0], r[(j + 0) & 31], uwf);
  float a1 = wx[1] * r[(j + 1) & 31];
  float a2 = wx[2] * r[(j + 2) & 31];
  float a3 = wx[3] * r[(j + 3) & 31];
  float a4 = wx[4] * r[(j + 4) & 31];
  float a5 = wx[5] * r[(j + 5) & 31];
  #pragma unroll
  for (int i = 6; i < OBS; i += 6) {
    a0 = fmaf(wx[i],     r[(j + i)     & 31], a0);
    a1 = fmaf(wx[i + 1], r[(j + i + 1) & 31], a1);
    a2 = fmaf(wx[i + 2], r[(j + i + 2) & 31], a2);
    a3 = fmaf(wx[i + 3], r[(j + i + 3) & 31], a3);
    a4 = fmaf(wx[i + 4], r[(j + i + 4) & 31], a4);
    a5 = fmaf(wx[i + 5], r[(j + i + 5) & 31], a5);
  }
  float out = ((a0 + a1) + (a2 + a3)) + (a4 + a5);
  r[(j + 30) & 31] = out;   // becomes s_{t+1}[29]
  return out;
}

// A^64 via 30 unit-state homogeneous chains (lanes 0..31 of one extra block).
__device__ __forceinline__ void compute_A64(const float* __restrict__ Wx) {
  const int k = threadIdx.x;
  float wx[OBS];
  #pragma unroll
  for (int i = 0; i < OBS; ++i) wx[i] = Wx[i];
  float r[32];
  #pragma unroll
  for (int i = 0; i < 32; ++i) r[i] = (k < OBS && i == k) ? 1.f : 0.f;
  #pragma unroll
  for (int j = 0; j < 32; ++j) step6(r, wx, j, 0.f);
  #pragma unroll
  for (int j = 0; j < 32; ++j) {
    float o = step6(r, wx, j, 0.f);          // global step t = 32 + j
    if (j >= 2) g_A[(j - 2) * 32 + k] = o;   // rows t-34 = 0..29
  }
}

// ---- pass A: zero-init chunk recurrence -> particular final states p_c ----
__global__ void __launch_bounds__(256, 4) k_passA(const float* __restrict__ u,
                                                  const float* __restrict__ Wx,
                                                  const float* __restrict__ Wf) {
  if (blockIdx.x == NBLK) { if (threadIdx.x < 32) compute_A64(Wx); return; }
  __shared__ float lds[256 * PAD];    // 36.9 KB -> 4 blocks/CU
  const int t  = threadIdx.x;
  const int n0 = blockIdx.x * 256;    // first chain of this block
  float wx[OBS];
  #pragma unroll
  for (int i = 0; i < OBS; ++i) wx[i] = Wx[i];
  const float wf = Wf[0];
  float r[32];
  #pragma unroll
  for (int i = 0; i < 32; ++i) r[i] = 0.f;

  #pragma unroll
  for (int R = 0; R < 2; ++R) {       // two 32-step tile rounds
    const int S = R * 32;
    // coalesced stage: wave covers 8 consecutive chains' 128B sub-rows
    #pragma unroll
    for (int i = 0; i < 8; ++i) {
      int f = i * 256 + t, ch = f >> 3, q = f & 7;
      float4 v = *(const float4*)(u + (size_t)(n0 + ch) * LCH + S + 4 * q);
      *(float4*)(&lds[ch * PAD + 4 * q]) = v;
    }
    __syncthreads();
    #pragma unroll
    for (int q = 0; q < 8; ++q) {
      float4 uv = *(const float4*)(&lds[t * PAD + 4 * q]);
      step6(r, wx, 4 * q + 0, wf * uv.x);
      step6(r, wx, 4 * q + 1, wf * uv.y);
      step6(r, wx, 4 * q + 2, wf * uv.z);
      step6(r, wx, 4 * q + 3, wf * uv.w);
    }
    __syncthreads();
  }
  // 64 steps -> ring realigned: state i at r[i] (r[30],r[31] junk-but-finite).
  // Route state store through LDS for fully coalesced g_ps writes.
  #pragma unroll
  for (int q = 0; q < 8; ++q)
    *(float4*)(&lds[t * PAD + 4 * q]) =
        make_float4(r[4 * q], r[4 * q + 1], r[4 * q + 2], r[4 * q + 3]);
  __syncthreads();
  #pragma unroll
  for (int i = 0; i < 8; ++i) {
    int f = i * 256 + t, ch = f >> 3, q = f & 7;
    *(float4*)(g_ps + (size_t)(n0 + ch) * 32 + 4 * q) =
        *(const float4*)(&lds[ch * PAD + 4 * q]);
  }
}

// ---- scan: s_{c+1} = A^64 s_c + p_c, in place over g_ps; 32 lanes/row ----
__global__ void __launch_bounds__(256, 4) k_scan(const float* __restrict__ x0) {
  const int tid = blockIdx.x * 256 + threadIdx.x;
  const int b = tid >> 5, k = tid & 31;
  float arow[OBS];
  #pragma unroll
  for (int j = 0; j < OBS; ++j)
    arow[j] = (k < OBS) ? g_A[k * 32 + j] : 0.f;
  #pragma unroll
  for (int j = 0; j < OBS; ++j)
    asm volatile("" : "+v"(arow[j]));   // pin in VGPRs: forbid remat into loop
  float s = (k < OBS) ? x0[(size_t)b * OBS + k] : 0.f;
  const size_t base = (size_t)b * CCH * 32 + k;
  float pn = g_ps[base];                // prefetch c=0
  #pragma unroll 1
  for (int c = 0; c < CCH; ++c) {
    float p = pn;
    if (c + 1 < CCH) pn = g_ps[base + (size_t)(c + 1) * 32];  // off serial path
    g_ps[base + (size_t)c * 32] = s;    // overwrite p_c with s_c
    float a0 = fmaf(arow[0], __shfl(s, 0, 32), p);
    float a1 = arow[1] * __shfl(s, 1, 32);
    float a2 = arow[2] * __shfl(s, 2, 32);
    float a3 = arow[3] * __shfl(s, 3, 32);
    float a4 = arow[4] * __shfl(s, 4, 32);
    float a5 = arow[5] * __shfl(s, 5, 32);
    #pragma unroll
    for (int j = 6; j < OBS; j += 6) {
      a0 = fmaf(arow[j],     __shfl(s, j,     32), a0);
      a1 = fmaf(arow[j + 1], __shfl(s, j + 1, 32), a1);
      a2 = fmaf(arow[j + 2], __shfl(s, j + 2, 32), a2);
      a3 = fmaf(arow[j + 3], __shfl(s, j + 3, 32), a3);
      a4 = fmaf(arow[j + 4], __shfl(s, j + 4, 32), a4);
      a5 = fmaf(arow[j + 5], __shfl(s, j + 5, 32), a5);
    }
    s = ((a0 + a1) + (a2 + a3)) + (a4 + a5);
  }
}

// ---- pass C: re-run each chunk from true start state, write outputs ----
__global__ void __launch_bounds__(256, 4) k_passC(const float* __restrict__ u,
                                                  const float* __restrict__ Wx,
                                                  const float* __restrict__ Wf,
                                                  float* __restrict__ out) {
  __shared__ float lds[256 * PAD];
  const int t  = threadIdx.x;
  const int n0 = blockIdx.x * 256;
  float wx[OBS];
  #pragma unroll
  for (int i = 0; i < OBS; ++i) wx[i] = Wx[i];
  const float wf = Wf[0];

  // cooperative coalesced load of this block's 256 start states
  #pragma unroll
  for (int i = 0; i < 8; ++i) {
    int f = i * 256 + t, ch = f >> 3, q = f & 7;
    *(float4*)(&lds[ch * PAD + 4 * q]) =
        *(const float4*)(g_ps + (size_t)(n0 + ch) * 32 + 4 * q);
  }
  __syncthreads();
  float r[32];
  #pragma unroll
  for (int q = 0; q < 8; ++q) {
    float4 v = *(const float4*)(&lds[t * PAD + 4 * q]);
    r[4 * q] = v.x; r[4 * q + 1] = v.y; r[4 * q + 2] = v.z; r[4 * q + 3] = v.w;
  }
  __syncthreads();
  // r[30],r[31] junk-but-finite: step j=0 reads r[0..29] only and overwrites
  // r[30] at j=0, r[31] at j=1 before any read.

  #pragma unroll
  for (int R = 0; R < 2; ++R) {
    const int S = R * 32;
    #pragma unroll
    for (int i = 0; i < 8; ++i) {
      int f = i * 256 + t, ch = f >> 3, q = f & 7;
      float4 v = *(const float4*)(u + (size_t)(n0 + ch) * LCH + S + 4 * q);
      *(float4*)(&lds[ch * PAD + 4 * q]) = v;
    }
    __syncthreads();
    #pragma unroll
    for (int q = 0; q < 8; ++q) {
      float4 uv = *(const float4*)(&lds[t * PAD + 4 * q]);
      float4 o4;
      o4.x = step6(r, wx, 4 * q + 0, wf * uv.x);
      o4.y = step6(r, wx, 4 * q + 1, wf * uv.y);
      o4.z = step6(r, wx, 4 * q + 2, wf * uv.z);
      o4.w = step6(r, wx, 4 * q + 3, wf * uv.w);
      *(float4*)(&lds[t * PAD + 4 * q]) = o4;   // in-place output tile
    }
    __syncthreads();
    #pragma unroll
    for (int i = 0; i < 8; ++i) {
      int f = i * 256 + t, ch = f >> 3, q = f & 7;
      *(float4*)(out + (size_t)(n0 + ch) * LCH + S + 4 * q) =
          *(const float4*)(&lds[ch * PAD + 4 * q]);
    }
    __syncthreads();
  }
}

extern "C" void kernel_launch(void* const* d_in, const int* in_sizes, int n_in,
                              void* d_out, int out_size, void* d_ws, size_t ws_size,
                              hipStream_t stream) {
  const float* u  = (const float*)d_in[0];
  const float* x0 = (const float*)d_in[1];
  const float* Wx = (const float*)d_in[2];
  const float* Wf = (const float*)d_in[3];
  float* out = (float*)d_out;

  hipLaunchKernelGGL(k_passA, dim3(NBLK + 1),       dim3(256), 0, stream, u, Wx, Wf);
  hipLaunchKernelGGL(k_scan,  dim3(NB * 32 / 256),  dim3(256), 0, stream, x0);
  hipLaunchKernelGGL(k_passC, dim3(NBLK),           dim3(256), 0, stream, u, Wx, Wf, out);
}

// Round 6
// 80.420 us; speedup vs baseline: 2.2102x; 1.3310x over previous
//
#include <hip/hip_runtime.h>

#define NB   8192
#define NT   2048
#define OBS  30
#define LCH  64               // chunk length
#define CCH  32               // chunks per row (LCH*CCH == NT)
#define NCHAIN (NB*CCH)       // 262144 chains
#define NBLK   (NCHAIN/256)   // 1024 work blocks
#define PAD  36               // LDS row stride (floats): 144B, 16B-aligned for b128

// Scratch: passA writes particular chunk-final states p_c, k_scan overwrites
// in place with true chunk-start states s_c, passC reads. [(b*CCH+c)*32+k]
__device__ float g_ps[(size_t)NCHAIN * 32];
__device__ float g_A [OBS * 32];   // A^64: g_A[i*32+j] = coeff s_c[j] -> s_{c+1}[i]

// One recurrence step on a 32-slot register ring, 6 accumulator chains.
// Invariant: before step t, state s_t[i] lives at r[(t+i)&31], i=0..29.
// j == t mod 32 must be a compile-time constant (callers fully unroll).
__device__ __forceinline__ float step6(float (&r)[32], const float (&wx)[OBS],
                                       int j, float uwf) {
  float a0 = fmaf(wx[0], r[(j + 0) & 31], uwf);
  float a1 = wx[1] * r[(j + 1) & 31];
  float a2 = wx[2] * r[(j + 2) & 31];
  float a3 = wx[3] * r[(j + 3) & 31];
  float a4 = wx[4] * r[(j + 4) & 31];
  float a5 = wx[5] * r[(j + 5) & 31];
  #pragma unroll
  for (int i = 6; i < OBS; i += 6) {
    a0 = fmaf(wx[i],     r[(j + i)     & 31], a0);
    a1 = fmaf(wx[i + 1], r[(j + i + 1) & 31], a1);
    a2 = fmaf(wx[i + 2], r[(j + i + 2) & 31], a2);
    a3 = fmaf(wx[i + 3], r[(j + i + 3) & 31], a3);
    a4 = fmaf(wx[i + 4], r[(j + i + 4) & 31], a4);
    a5 = fmaf(wx[i + 5], r[(j + i + 5) & 31], a5);
  }
  float out = ((a0 + a1) + (a2 + a3)) + (a4 + a5);
  r[(j + 30) & 31] = out;   // becomes s_{t+1}[29]
  return out;
}

// A^64 via 30 unit-state homogeneous chains (lanes 0..31 of one extra block).
__device__ __forceinline__ void compute_A64(const float* __restrict__ Wx) {
  const int k = threadIdx.x;
  float wx[OBS];
  #pragma unroll
  for (int i = 0; i < OBS; ++i) wx[i] = Wx[i];
  float r[32];
  #pragma unroll
  for (int i = 0; i < 32; ++i) r[i] = (k < OBS && i == k) ? 1.f : 0.f;
  #pragma unroll
  for (int j = 0; j < 32; ++j) step6(r, wx, j, 0.f);
  #pragma unroll
  for (int j = 0; j < 32; ++j) {
    float o = step6(r, wx, j, 0.f);          // global step t = 32 + j
    if (j >= 2) g_A[(j - 2) * 32 + k] = o;   // rows t-34 = 0..29
  }
}

// ---- pass A: zero-init chunk recurrence -> particular final states p_c ----
__global__ void __launch_bounds__(256, 4) k_passA(const float* __restrict__ u,
                                                  const float* __restrict__ Wx,
                                                  const float* __restrict__ Wf) {
  if (blockIdx.x == NBLK) { if (threadIdx.x < 32) compute_A64(Wx); return; }
  __shared__ float lds[256 * PAD];    // 36.9 KB -> 4 blocks/CU
  const int t  = threadIdx.x;
  const int n0 = blockIdx.x * 256;    // first chain of this block
  float wx[OBS];
  #pragma unroll
  for (int i = 0; i < OBS; ++i) wx[i] = Wx[i];
  const float wf = Wf[0];
  float r[32];
  #pragma unroll
  for (int i = 0; i < 32; ++i) r[i] = 0.f;

  #pragma unroll
  for (int R = 0; R < 2; ++R) {       // two 32-step tile rounds
    const int S = R * 32;
    // coalesced stage: wave covers 8 consecutive chains' 128B sub-rows
    #pragma unroll
    for (int i = 0; i < 8; ++i) {
      int f = i * 256 + t, ch = f >> 3, q = f & 7;
      float4 v = *(const float4*)(u + (size_t)(n0 + ch) * LCH + S + 4 * q);
      *(float4*)(&lds[ch * PAD + 4 * q]) = v;
    }
    __syncthreads();
    #pragma unroll
    for (int q = 0; q < 8; ++q) {
      float4 uv = *(const float4*)(&lds[t * PAD + 4 * q]);
      step6(r, wx, 4 * q + 0, wf * uv.x);
      step6(r, wx, 4 * q + 1, wf * uv.y);
      step6(r, wx, 4 * q + 2, wf * uv.z);
      step6(r, wx, 4 * q + 3, wf * uv.w);
    }
    __syncthreads();
  }
  // 64 steps -> ring realigned: state i at r[i] (r[30],r[31] junk-but-finite).
  // Route state store through LDS for fully coalesced g_ps writes.
  #pragma unroll
  for (int q = 0; q < 8; ++q)
    *(float4*)(&lds[t * PAD + 4 * q]) =
        make_float4(r[4 * q], r[4 * q + 1], r[4 * q + 2], r[4 * q + 3]);
  __syncthreads();
  #pragma unroll
  for (int i = 0; i < 8; ++i) {
    int f = i * 256 + t, ch = f >> 3, q = f & 7;
    *(float4*)(g_ps + (size_t)(n0 + ch) * 32 + 4 * q) =
        *(const float4*)(&lds[ch * PAD + 4 * q]);
  }
}

// ---- scan: s_{c+1} = A^64 s_c + p_c, in place over g_ps ----
// 32 lanes per batch row. Cross-lane state broadcast via a per-group LDS
// slot: lane k writes s[k], all lanes read the full 32-float state back
// with broadcast ds_read_b128 (wave-synchronous: both groups of a wave64
// advance in lockstep, no barrier). Dot product is pure register FMAs.
__global__ void __launch_bounds__(256, 4) k_scan(const float* __restrict__ x0) {
  __shared__ float sbuf[8 * 32];      // one 128B state slot per group
  const int tid = blockIdx.x * 256 + threadIdx.x;
  const int b = tid >> 5;             // batch row
  const int g = threadIdx.x >> 5;     // group within block
  const int k = threadIdx.x & 31;     // lane within group
  float* sb = &sbuf[g * 32];

  float arow[OBS];
  #pragma unroll
  for (int j = 0; j < OBS; ++j)
    arow[j] = (k < OBS) ? g_A[k * 32 + j] : 0.f;
  float s = (k < OBS) ? x0[(size_t)b * OBS + k] : 0.f;
  const size_t base = (size_t)b * CCH * 32 + k;
  float pn = g_ps[base];              // prefetch p_0

  #pragma unroll 1
  for (int c = 0; c < CCH; ++c) {
    float p = pn;
    sb[k] = s;                          // publish own component
    g_ps[base + (size_t)c * 32] = s;    // persist s_c (overwrite p_c)
    if (c + 1 < CCH) pn = g_ps[base + (size_t)(c + 1) * 32];  // off serial path
    float sv[32];
    #pragma unroll
    for (int q = 0; q < 8; ++q) {       // broadcast reads: conflict-free
      float4 v = *(const float4*)(&sb[4 * q]);
      sv[4 * q] = v.x; sv[4 * q + 1] = v.y;
      sv[4 * q + 2] = v.z; sv[4 * q + 3] = v.w;
    }
    float a0 = fmaf(arow[0], sv[0], p);
    float a1 = arow[1] * sv[1];
    float a2 = arow[2] * sv[2];
    float a3 = arow[3] * sv[3];
    float a4 = arow[4] * sv[4];
    float a5 = arow[5] * sv[5];
    #pragma unroll
    for (int j = 6; j < OBS; j += 6) {
      a0 = fmaf(arow[j],     sv[j],     a0);
      a1 = fmaf(arow[j + 1], sv[j + 1], a1);
      a2 = fmaf(arow[j + 2], sv[j + 2], a2);
      a3 = fmaf(arow[j + 3], sv[j + 3], a3);
      a4 = fmaf(arow[j + 4], sv[j + 4], a4);
      a5 = fmaf(arow[j + 5], sv[j + 5], a5);
    }
    s = ((a0 + a1) + (a2 + a3)) + (a4 + a5);
    // lanes k>=30: arow==0 -> s = p (junk-but-finite), never used in dots
  }
}

// ---- pass C: re-run each chunk from true start state, write outputs ----
__global__ void __launch_bounds__(256, 4) k_passC(const float* __restrict__ u,
                                                  const float* __restrict__ Wx,
                                                  const float* __restrict__ Wf,
                                                  float* __restrict__ out) {
  __shared__ float lds[256 * PAD];
  const int t  = threadIdx.x;
  const int n0 = blockIdx.x * 256;
  float wx[OBS];
  #pragma unroll
  for (int i = 0; i < OBS; ++i) wx[i] = Wx[i];
  const float wf = Wf[0];

  // cooperative coalesced load of this block's 256 start states
  #pragma unroll
  for (int i = 0; i < 8; ++i) {
    int f = i * 256 + t, ch = f >> 3, q = f & 7;
    *(float4*)(&lds[ch * PAD + 4 * q]) =
        *(const float4*)(g_ps + (size_t)(n0 + ch) * 32 + 4 * q);
  }
  __syncthreads();
  float r[32];
  #pragma unroll
  for (int q = 0; q < 8; ++q) {
    float4 v = *(const float4*)(&lds[t * PAD + 4 * q]);
    r[4 * q] = v.x; r[4 * q + 1] = v.y; r[4 * q + 2] = v.z; r[4 * q + 3] = v.w;
  }
  __syncthreads();
  // r[30],r[31] junk-but-finite: step j=0 reads r[0..29] only and overwrites
  // r[30] at j=0, r[31] at j=1 before any read.

  #pragma unroll
  for (int R = 0; R < 2; ++R) {
    const int S = R * 32;
    #pragma unroll
    for (int i = 0; i < 8; ++i) {
      int f = i * 256 + t, ch = f >> 3, q = f & 7;
      float4 v = *(const float4*)(u + (size_t)(n0 + ch) * LCH + S + 4 * q);
      *(float4*)(&lds[ch * PAD + 4 * q]) = v;
    }
    __syncthreads();
    #pragma unroll
    for (int q = 0; q < 8; ++q) {
      float4 uv = *(const float4*)(&lds[t * PAD + 4 * q]);
      float4 o4;
      o4.x = step6(r, wx, 4 * q + 0, wf * uv.x);
      o4.y = step6(r, wx, 4 * q + 1, wf * uv.y);
      o4.z = step6(r, wx, 4 * q + 2, wf * uv.z);
      o4.w = step6(r, wx, 4 * q + 3, wf * uv.w);
      *(float4*)(&lds[t * PAD + 4 * q]) = o4;   // in-place output tile
    }
    __syncthreads();
    #pragma unroll
    for (int i = 0; i < 8; ++i) {
      int f = i * 256 + t, ch = f >> 3, q = f & 7;
      *(float4*)(out + (size_t)(n0 + ch) * LCH + S + 4 * q) =
          *(const float4*)(&lds[ch * PAD + 4 * q]);
    }
    __syncthreads();
  }
}

extern "C" void kernel_launch(void* const* d_in, const int* in_sizes, int n_in,
                              void* d_out, int out_size, void* d_ws, size_t ws_size,
                              hipStream_t stream) {
  const float* u  = (const float*)d_in[0];
  const float* x0 = (const float*)d_in[1];
  const float* Wx = (const float*)d_in[2];
  const float* Wf = (const float*)d_in[3];
  float* out = (float*)d_out;

  hipLaunchKernelGGL(k_passA, dim3(NBLK + 1),       dim3(256), 0, stream, u, Wx, Wf);
  hipLaunchKernelGGL(k_scan,  dim3(NB * 32 / 256),  dim3(256), 0, stream, x0);
  hipLaunchKernelGGL(k_passC, dim3(NBLK),           dim3(256), 0, stream, u, Wx, Wf, out);
}